// Round 5
// baseline (267.093 us; speedup 1.0000x reference)
//
#include <hip/hip_runtime.h>
#include <math.h>

// DigitCaps dynamic routing, MI355X (gfx950). Round 5: no-workspace pipeline.
// B=256, I=1152 (dim 8), O=10 (dim 16), 3 routing iters.
//
// Key facts driving this round (from round-4 counters):
//  - k_uhat was ws-WRITE-bound (103.7 MB at 2.25 TB/s); u_hat recompute is
//    only ~0.75 GFLOP => rematerialize instead of store. No 94 MB ws.
//  - k_route was DS-pipe-bound (360 ds_swizzle/thread from __shfl_xor).
//    16-lane d-reductions now use DPP (quad_perm xor1/xor2 + row_ror 4/8),
//    which runs at VALU rate with zero LDS traffic.
//
// b_ij identity: logits at iter k = u . (v0+..+v_{k-1}) = u . vsum -> b_ij is
// never materialized; vsum[256][160] lives in ws (tiny).
//
// Pipeline (6 kernels):
//  K1 k_pass<0>: u = W@x, partial[72][256][160] = per-itile sums of u.
//  K2 k_squash<0>: reduce 72, *0.1, squash -> vsum = v0.
//  K3 k_pass<1>: recompute u, c = softmax_o(u.vsum), partial = sums of c*u.
//  K4 k_squash<1>: vsum += v1.
//  K5 k_pass<1> again.
//  K6 k_squash<2>: out = v2.

constexpr int Bc  = 256;
constexpr int Ic  = 1152;
constexpr int Oc  = 10;
constexpr int DOc = 16;
constexpr int ODc = 160;
constexpr int ITILES = 72;

// Sum over the 16-lane group (lanes sharing t>>4), result in all 16 lanes.
// quad_perm xor1 (0xB1), quad_perm xor2 (0x4E), row_ror:4 (0x124), row_ror:8
// (0x128). All within a DPP row of 16 -> valid for our aligned 16-lane groups.
__device__ __forceinline__ float dpp16_sum(float v) {
    int s;
    s = __builtin_amdgcn_update_dpp(0, __float_as_int(v), 0xB1, 0xF, 0xF, true);
    v += __int_as_float(s);
    s = __builtin_amdgcn_update_dpp(0, __float_as_int(v), 0x4E, 0xF, 0xF, true);
    v += __int_as_float(s);
    s = __builtin_amdgcn_update_dpp(0, __float_as_int(v), 0x124, 0xF, 0xF, true);
    v += __int_as_float(s);
    s = __builtin_amdgcn_update_dpp(0, __float_as_int(v), 0x128, 0xF, 0xF, true);
    v += __int_as_float(s);
    return v;
}

// ---------------------------------------------------------------- K1/K3/K5
// grid 1152 = 72 itiles x 16 btiles, 256 threads.
// Thread (il = t>>4, d = t&15) owns capsule i = itile*16+il, out-dim d; its
// 80 W floats live in registers and are reused across the 16 b of the btile.
template <int PASS>
__global__ __launch_bounds__(256, 2) void k_pass(const float* __restrict__ x,
                                                 const float* __restrict__ W,
                                                 const float* __restrict__ vsum,
                                                 float* __restrict__ partial) {
    const int bx    = blockIdx.x;
    const int itile = bx % ITILES;      // 72%8==0: itile spreads across XCDs
    const int btile = bx / ITILES;
    const int t     = threadIdx.x;
    const int d     = t & 15;
    const int il    = t >> 4;
    const int w     = t >> 6;
    const int i     = itile * 16 + il;
    const int b0    = btile * 16;

    __shared__ __align__(16) float xs[16 * 128];        //  8 KB [bb][il*8+k]
    __shared__ __align__(16) float pacc[4 * 16 * ODc];  // 40 KB [w][bb][od]
    __shared__ __align__(16) float vs_s[16 * ODc];      // 10 KB [bb][od]

    // stage x[b0:b0+16][itile*16:+16][8]
#pragma unroll
    for (int j = 0; j < 2; ++j) {
        int e  = t + j * 256;           // float4 index, 512 total
        int bb = e >> 5;
        int r  = e & 31;
        ((float4*)xs)[e] =
            ((const float4*)(x + (size_t)(b0 + bb) * (Ic * 8) + itile * 128))[r];
    }
    if (PASS == 1) {
        // vsum rows for b0..b0+15: 2560 contiguous floats = 640 float4
        const float4* vg = (const float4*)(vsum + (size_t)b0 * ODc);
#pragma unroll
        for (int j = 0; j < 3; ++j) {
            int e = t + j * 256;
            if (e < 640) ((float4*)vs_s)[e] = vg[e];
        }
    }

    // W fragment for (i, d): 10 o x 8 k = 80 floats in registers
    float4 wr[20];
    {
        const float4* wp = (const float4*)(W + (((size_t)i * Oc) * DOc + d) * 8);
#pragma unroll
        for (int o = 0; o < Oc; ++o) {
            wr[2 * o]     = wp[o * 32];
            wr[2 * o + 1] = wp[o * 32 + 1];
        }
    }
    __syncthreads();

#pragma unroll 1
    for (int bb = 0; bb < 16; ++bb) {
        const float4 xa = *((const float4*)(xs + bb * 128 + il * 8));
        const float4 xb = *((const float4*)(xs + bb * 128 + il * 8 + 4));
        float u[Oc];
#pragma unroll
        for (int o = 0; o < Oc; ++o) {
            float4 w0 = wr[2 * o], w1 = wr[2 * o + 1];
            u[o] = w0.x * xa.x + w0.y * xa.y + w0.z * xa.z + w0.w * xa.w +
                   w1.x * xb.x + w1.y * xb.y + w1.z * xb.z + w1.w * xb.w;
        }
        float contrib[Oc];
        if (PASS == 1) {
            // logits via DPP 16-lane reduce (VALU, no DS traffic)
            float c[Oc];
#pragma unroll
            for (int o = 0; o < Oc; ++o)
                c[o] = dpp16_sum(u[o] * vs_s[bb * ODc + o * 16 + d]);
            float m = c[0];
#pragma unroll
            for (int o = 1; o < Oc; ++o) m = fmaxf(m, c[o]);
            float se = 0.f;
#pragma unroll
            for (int o = 0; o < Oc; ++o) {
                c[o] = __expf(c[o] - m);
                se += c[o];
            }
            const float inv = 1.f / se;
#pragma unroll
            for (int o = 0; o < Oc; ++o) contrib[o] = (c[o] * inv) * u[o];
        } else {
            // iter 0: softmax(0) = 1/10 exactly; the 0.1 is folded into
            // k_squash's `pre`.
#pragma unroll
            for (int o = 0; o < Oc; ++o) contrib[o] = u[o];
        }
        // reduce over the wave's 4 il values (cross-row -> DS shuffles)
#pragma unroll
        for (int o = 0; o < Oc; ++o) {
            float a = contrib[o];
            a += __shfl_xor(a, 16);
            a += __shfl_xor(a, 32);
            if ((t & 63) < 16) pacc[(w * 16 + bb) * ODc + o * 16 + d] = a;
        }
    }
    __syncthreads();
    // partial[itile][b0+bb][od]
#pragma unroll
    for (int j = 0; j < 10; ++j) {
        int e = t + j * 256;            // bb*160+od, 2560 total
        float s = pacc[e] + pacc[2560 + e] + pacc[5120 + e] + pacc[7680 + e];
        partial[(size_t)itile * (Bc * ODc) + b0 * ODc + e] = s;
    }
}

// ---------------------------------------------------------------- K2/K4/K6
// MODE 0: vsum = v   MODE 1: vsum += v   MODE 2: out = v
template <int MODE>
__global__ __launch_bounds__(256) void k_squash(const float* __restrict__ part,
                                                float* __restrict__ vsum,
                                                float* __restrict__ out,
                                                float pre) {
    const int b = blockIdx.x;
    const int t = threadIdx.x;
    if (t >= ODc) return;
    float s = 0.f;
#pragma unroll 8
    for (int p = 0; p < ITILES; ++p)
        s += part[(size_t)p * (Bc * ODc) + b * ODc + t];
    s *= pre;
    float sq = dpp16_sum(s * s);
    float scale = sq / ((1.f + sq) * sqrtf(sq));
    float v = s * scale;
    if (MODE == 0) vsum[b * ODc + t] = v;
    if (MODE == 1) vsum[b * ODc + t] += v;
    if (MODE == 2) out[(size_t)b * ODc + t] = v;
}

// ---------------------------------------------------------------- fallback
// Single-kernel W-recompute version (no ws needed beyond nothing) — used only
// if ws_size is tiny. Same as round 4's fallback.
__global__ void __launch_bounds__(1024, 4)
digitcaps_fallback(const float* __restrict__ x, const float* __restrict__ W,
                   float* __restrict__ out) {
    const int b = blockIdx.x, t = threadIdx.x;
    const int lane = t & 63, wid = t >> 6, d = t & 15, iblk = t >> 4;
    __shared__ __align__(16) float xs[Ic * 8];
    __shared__ __align__(16) float red[16 * ODc];
    __shared__ __align__(16) float svec[ODc], vcur[ODc], vsum[ODc];
    {
        const float4* xg = (const float4*)(x + (size_t)b * (Ic * 8));
        float4* xl = (float4*)xs;
        for (int j = t; j < Ic * 2; j += 1024) xl[j] = xg[j];
    }
    if (t < ODc) vsum[t] = 0.f;
    __syncthreads();
    float acc[Oc], vsr[Oc];
    for (int it = 0; it < 3; ++it) {
#pragma unroll
        for (int o = 0; o < Oc; ++o) { acc[o] = 0.f; vsr[o] = vsum[o * 16 + d]; }
#pragma unroll 1
        for (int chk = 0; chk < 18; ++chk) {
            const int i = chk * 64 + iblk;
            const float4 xa = ((const float4*)(xs + i * 8))[0];
            const float4 xb = ((const float4*)(xs + i * 8))[1];
            const float* wb = W + (((size_t)i * Oc) * DOc + d) * 8;
            float uo[Oc];
#pragma unroll
            for (int o = 0; o < Oc; ++o) {
                const float4* wp = (const float4*)(wb + o * 128);
                float4 w0 = wp[0], w1 = wp[1];
                uo[o] = w0.x * xa.x + w0.y * xa.y + w0.z * xa.z + w0.w * xa.w +
                        w1.x * xb.x + w1.y * xb.y + w1.z * xb.z + w1.w * xb.w;
            }
            float cc[Oc];
            if (it > 0) {
#pragma unroll
                for (int o = 0; o < Oc; ++o) cc[o] = dpp16_sum(uo[o] * vsr[o]);
                float m = cc[0];
#pragma unroll
                for (int o = 1; o < Oc; ++o) m = fmaxf(m, cc[o]);
                float se = 0.f;
#pragma unroll
                for (int o = 0; o < Oc; ++o) { cc[o] = __expf(cc[o] - m); se += cc[o]; }
                float inv = 1.f / se;
#pragma unroll
                for (int o = 0; o < Oc; ++o) acc[o] += cc[o] * inv * uo[o];
            } else {
#pragma unroll
                for (int o = 0; o < Oc; ++o) acc[o] += 0.1f * uo[o];
            }
        }
#pragma unroll
        for (int o = 0; o < Oc; ++o) {
            float a = acc[o];
            a += __shfl_xor(a, 16);
            a += __shfl_xor(a, 32);
            if (lane < 16) red[wid * ODc + o * 16 + lane] = a;
        }
        __syncthreads();
        if (t < ODc) {
            float s = 0.f;
#pragma unroll
            for (int w = 0; w < 16; ++w) s += red[w * ODc + t];
            svec[t] = s;
        }
        __syncthreads();
        if (t < Oc) {
            float sq = 0.f;
#pragma unroll
            for (int dd = 0; dd < DOc; ++dd) sq += svec[t * 16 + dd] * svec[t * 16 + dd];
            float sc = sq / ((1.f + sq) * sqrtf(sq));
#pragma unroll
            for (int dd = 0; dd < DOc; ++dd) {
                float v = svec[t * 16 + dd] * sc;
                vcur[t * 16 + dd] = v;
                vsum[t * 16 + dd] += v;
            }
        }
        __syncthreads();
    }
    if (t < ODc) out[(size_t)b * ODc + t] = vcur[t];
}

// ---------------------------------------------------------------- launcher
extern "C" void kernel_launch(void* const* d_in, const int* in_sizes, int n_in,
                              void* d_out, int out_size, void* d_ws, size_t ws_size,
                              hipStream_t stream) {
    (void)in_sizes; (void)n_in; (void)out_size;
    const float* x = (const float*)d_in[0];   // [256,1152,8]
    const float* W = (const float*)d_in[1];   // [1152,10,16,8]
    float* out     = (float*)d_out;           // [256,10,16]

    const size_t PART_B = (size_t)ITILES * Bc * ODc * sizeof(float); // 11.8 MB
    const size_t VSUM_B = (size_t)Bc * ODc * sizeof(float);          // 160 KB

    float* partial = (float*)d_ws;
    float* vsum    = (float*)((char*)d_ws + PART_B);

    if (ws_size >= PART_B + VSUM_B) {
        dim3 pg(ITILES * 16), pb(256);
        hipLaunchKernelGGL((k_pass<0>), pg, pb, 0, stream, x, W, nullptr, partial);
        hipLaunchKernelGGL((k_squash<0>), dim3(Bc), dim3(256), 0, stream,
                           partial, vsum, out, 0.1f);
        hipLaunchKernelGGL((k_pass<1>), pg, pb, 0, stream, x, W, vsum, partial);
        hipLaunchKernelGGL((k_squash<1>), dim3(Bc), dim3(256), 0, stream,
                           partial, vsum, out, 1.f);
        hipLaunchKernelGGL((k_pass<1>), pg, pb, 0, stream, x, W, vsum, partial);
        hipLaunchKernelGGL((k_squash<2>), dim3(Bc), dim3(256), 0, stream,
                           partial, vsum, out, 1.f);
    } else {
        hipLaunchKernelGGL(digitcaps_fallback, dim3(Bc), dim3(1024), 0, stream,
                           x, W, out);
    }
}